// Round 3
// baseline (433.894 us; speedup 1.0000x reference)
//
#include <hip/hip_runtime.h>
#include <hip/hip_bf16.h>

typedef unsigned short u16;
typedef __attribute__((ext_vector_type(8))) short short8;
typedef __attribute__((ext_vector_type(4))) float f32x4;

// ---------- helpers ----------
__device__ __forceinline__ float bf2f(u16 u){
  union { unsigned int i; float f; } v; v.i = ((unsigned int)u) << 16; return v.f;
}
__device__ __forceinline__ u16 f2bf(float f){
  union { float f; unsigned int i; } v; v.f = f;
  unsigned int x = v.i;
  return (u16)((x + 0x7fffu + ((x >> 16) & 1u)) >> 16);
}
__device__ __forceinline__ float gelu_exact(float x){
  return 0.5f * x * (1.0f + erff(x * 0.70710678118654752440f));
}

// B=32 N=320 C=768 H=12 S=256 T=64 hd=64; ALL I/O fp32.

// ---------- convert fp32 -> bf16 (x, qkv_w, proj_w copies for MFMA path) ----------
__global__ void k_cvt(const float* __restrict__ src, u16* __restrict__ dst, int n4){
  int i = blockIdx.x*256 + threadIdx.x;
  if (i < n4){
    float4 v = ((const float4*)src)[i];
    ushort4 p; p.x = f2bf(v.x); p.y = f2bf(v.y); p.z = f2bf(v.z); p.w = f2bf(v.w);
    ((ushort4*)dst)[i] = p;
  }
}

// ---------- tgt_rep[b][c] = mean_t(x[b,t,c]*mask[b,t]) ----------
__global__ void k_tgt(const float* __restrict__ x, const float* __restrict__ tmask,
                      float* __restrict__ tgt){
  int b = blockIdx.x;
  for (int c = threadIdx.x; c < 768; c += 256){
    float s = 0.f;
    for (int t = 0; t < 64; ++t)
      s += x[(size_t)(b*320 + t)*768 + c] * tmask[b*64 + t];
    tgt[b*768 + c] = s * (1.0f/64.0f);
  }
}

// ---------- tgtdp[b][o] = dp1_b[o] + sum_c tgt[b][c]*dp1_w[o][768+c] ----------
__global__ void k_tgtdp(const float* __restrict__ tgt, const float* __restrict__ w1,
                        const float* __restrict__ b1, float* __restrict__ tgtdp){
  int b = blockIdx.x; int o = threadIdx.x;   // blockDim = 384
  float s = b1[o];
  const float* wr = w1 + (size_t)o*1536 + 768;
  const float* tr = tgt + b*768;
  for (int c = 0; c < 768; ++c) s += tr[c] * wr[c];
  tgtdp[b*384 + o] = s;
}

// ---------- fp32 SGEMM 64x64 tile (decision path: precision-critical) ----------
// REMAP: map M-row r -> batch-search token row of x. HASB: add bias[n], else add tgtdp[batch][n].
template<int REMAP, int HASB>
__global__ __launch_bounds__(256)
void k_sgemm(const float* __restrict__ A, int lda,
             const float* __restrict__ BT, int ldb, int K,
             const float* __restrict__ bias, const float* __restrict__ tgtdp,
             float* __restrict__ out, int ldo)
{
  __shared__ float As[16][68];
  __shared__ float Bs[16][68];
  int mB = blockIdx.x*64, nB = blockIdx.y*64;
  int t = threadIdx.x;
  int tx = t & 15, ty = t >> 4;
  float acc[4][4] = {};
  for (int k0 = 0; k0 < K; k0 += 16){
    __syncthreads();
    {
      int m = t >> 2, kc = (t & 3) * 4;
      int ga = mB + m;
      if (REMAP) ga = ((ga >> 8) * 320) + 64 + (ga & 255);
      float4 av = *(const float4*)&A[(size_t)ga*lda + k0 + kc];
      As[kc+0][m] = av.x; As[kc+1][m] = av.y; As[kc+2][m] = av.z; As[kc+3][m] = av.w;
      float4 bv = *(const float4*)&BT[(size_t)(nB+m)*ldb + k0 + kc];
      Bs[kc+0][m] = bv.x; Bs[kc+1][m] = bv.y; Bs[kc+2][m] = bv.z; Bs[kc+3][m] = bv.w;
    }
    __syncthreads();
    #pragma unroll
    for (int k = 0; k < 16; ++k){
      float4 av = *(const float4*)&As[k][ty*4];
      float4 bv = *(const float4*)&Bs[k][tx*4];
      float a4[4] = {av.x, av.y, av.z, av.w};
      float b4[4] = {bv.x, bv.y, bv.z, bv.w};
      #pragma unroll
      for (int i = 0; i < 4; ++i)
        #pragma unroll
        for (int j = 0; j < 4; ++j)
          acc[i][j] += a4[i] * b4[j];
    }
  }
  #pragma unroll
  for (int i = 0; i < 4; ++i){
    int row = mB + ty*4 + i;
    #pragma unroll
    for (int j = 0; j < 4; ++j){
      int n = nB + tx*4 + j;
      float base = HASB ? bias[n] : tgtdp[(row >> 8)*384 + n];
      out[(size_t)row*ldo + n] = gelu_exact(acc[i][j] + base);
    }
  }
}

// ---------- decision: logits, argmax, one-hot (fp32 out), group ids ----------
__global__ void k_decide(const float* __restrict__ h2, const float* __restrict__ w3,
                         const float* __restrict__ b3, float* __restrict__ dec,
                         unsigned char* __restrict__ gid)
{
  int t = blockIdx.x*256 + threadIdx.x;   // 0..8191
  int b = t >> 8, s = t & 255;
  const float* hr = h2 + (size_t)t*192;
  float l0 = b3[0], l1 = b3[1];
  for (int c = 0; c < 192; ++c){
    float h = hr[c];
    l0 += h * w3[c];
    l1 += h * w3[192 + c];
  }
  int idx = (l1 > l0) ? 1 : 0;            // jnp.argmax: first max wins
  dec[t*2 + 0] = (idx == 0) ? 1.f : 0.f;
  dec[t*2 + 1] = (idx == 1) ? 1.f : 0.f;
  gid[b*320 + 64 + s] = (unsigned char)(2 + idx);
  if (s < 64) gid[b*320 + s] = 1;         // template tokens -> group 1
}

// ---------- bf16 MFMA GEMM, 128x128 tile, BK=32 (attention path) ----------
// MODE 0: qkv  — A=xb[10240,768], BT=qkvwb[2304,768]; +bias(f32), scatter to
//         Qg/Kg ([bh][j][d]) and Vg transposed ([bh][d][j]), bf16
// MODE 1: proj — A=aout(bf16)[10240,768], BT=projwb[768,768]; +bias -> fp32 d_out
template<int MODE>
__global__ __launch_bounds__(256, 2)
void k_gemm(const u16* __restrict__ A, const u16* __restrict__ BT,
            const float* __restrict__ bias, float* __restrict__ outp,
            u16* __restrict__ Qg, u16* __restrict__ Kg, u16* __restrict__ Vg)
{
  const int K = 768;
  const int LDK = 56;          // padded LDS stride (16B aligned rows)
  __shared__ u16 As[128*LDK];
  __shared__ u16 Bs[128*LDK];
  int mB = blockIdx.x*128, nB = blockIdx.y*128;
  int t = threadIdx.x;
  int w = t >> 6, l = t & 63;
  int wr = w >> 1, wc = w & 1;
  int lm = l & 15, lq = l >> 4;

  f32x4 zero4 = {0.f,0.f,0.f,0.f};
  f32x4 acc[4][4];
  #pragma unroll
  for (int i = 0; i < 4; ++i)
    #pragma unroll
    for (int j = 0; j < 4; ++j) acc[i][j] = zero4;

  for (int k0 = 0; k0 < K; k0 += 32){
    __syncthreads();
    #pragma unroll
    for (int r = 0; r < 2; ++r){
      int c = t + r*256;
      int row = c >> 2, kc = (c & 3) * 8;
      *(uint4*)&As[row*LDK + kc] = *(const uint4*)&A[(size_t)(mB+row)*768 + k0 + kc];
      *(uint4*)&Bs[row*LDK + kc] = *(const uint4*)&BT[(size_t)(nB+row)*768 + k0 + kc];
    }
    __syncthreads();
    short8 af[4], bfv[4];
    #pragma unroll
    for (int mt = 0; mt < 4; ++mt)
      af[mt] = *(const short8*)&As[(wr*64 + mt*16 + lm)*LDK + lq*8];
    #pragma unroll
    for (int nt = 0; nt < 4; ++nt)
      bfv[nt] = *(const short8*)&Bs[(wc*64 + nt*16 + lm)*LDK + lq*8];
    #pragma unroll
    for (int mt = 0; mt < 4; ++mt)
      #pragma unroll
      for (int nt = 0; nt < 4; ++nt)
        acc[mt][nt] = __builtin_amdgcn_mfma_f32_16x16x32_bf16(af[mt], bfv[nt], acc[mt][nt], 0, 0, 0);
  }

  // epilogue: C layout col=lane&15, row=(lane>>4)*4+reg
  #pragma unroll
  for (int mt = 0; mt < 4; ++mt){
    #pragma unroll
    for (int nt = 0; nt < 4; ++nt){
      int coln  = nB + wc*64 + nt*16 + lm;
      int rbase = mB + wr*64 + mt*16 + lq*4;
      float bv = bias[coln];
      if (MODE == 0){
        int bidx = rbase / 320;             // 4-row group never straddles a batch boundary
        int j = rbase - bidx*320;
        if (coln >= 1536){
          int h = (coln - 1536) >> 6, d = coln & 63;
          ushort4 pk;
          pk.x = f2bf(acc[mt][nt][0] + bv);
          pk.y = f2bf(acc[mt][nt][1] + bv);
          pk.z = f2bf(acc[mt][nt][2] + bv);
          pk.w = f2bf(acc[mt][nt][3] + bv);
          *(ushort4*)&Vg[((size_t)(bidx*12 + h)*64 + d)*320 + j] = pk;
        } else {
          bool isq = coln < 768;
          int ch = isq ? coln : (coln - 768);
          int h = ch >> 6, d = ch & 63;
          u16* dst = isq ? Qg : Kg;
          #pragma unroll
          for (int r = 0; r < 4; ++r)
            dst[((size_t)(bidx*12 + h)*320 + (j + r))*64 + d] = f2bf(acc[mt][nt][r] + bv);
        }
      } else {
        #pragma unroll
        for (int r = 0; r < 4; ++r)
          outp[(size_t)(rbase + r)*768 + coln] = acc[mt][nt][r] + bv;
      }
    }
  }
}

// ---------- attention per (b,h): policy-masked softmax, MFMA, bf16 ----------
__global__ __launch_bounds__(256, 1)
void k_attn(const u16* __restrict__ Qg, const u16* __restrict__ Kg,
            const u16* __restrict__ Vg, const unsigned char* __restrict__ gid,
            u16* __restrict__ aout)
{
  __shared__ u16 Ps[64*328];     // P (C-layout -> A-layout round-trip), padded
  __shared__ float vsp[4][64];
  __shared__ float vsum[64];
  __shared__ unsigned char gls[320];
  int bh = blockIdx.x;
  int b = bh / 12, h = bh % 12;
  int t = threadIdx.x, w = t >> 6, l = t & 63;
  int lm = l & 15, lq = l >> 4;
  const u16* Ksrc = Kg + (size_t)bh*320*64;   // [j][d]
  const u16* Vsrc = Vg + (size_t)bh*64*320;   // [d][j] (transposed)
  const u16* Qsrc = Qg + (size_t)bh*320*64;   // [j][d]

  for (int c = t; c < 320; c += 256) gls[c] = gid[b*320 + c];
  {
    int d = l, p = w;
    float s = 0.f;
    const u16* vr = Vsrc + (size_t)d*320 + p*80;
    for (int j = 0; j < 80; ++j) s += bf2f(vr[j]);
    vsp[p][d] = s;
  }
  __syncthreads();
  if (t < 64) vsum[t] = (vsp[0][t] + vsp[1][t] + vsp[2][t] + vsp[3][t]) * (1e-6f/320.f);
  __syncthreads();

  f32x4 zero4 = {0.f,0.f,0.f,0.f};
  const float cexp = 0.125f * 1.44269504088896340736f;  // scale * log2(e)

  for (int qt = 0; qt < 5; ++qt){
    int qb = qt*64 + w*16;                 // wave's 16 q rows
    const u16* qp = Qsrc + (size_t)(qb + lm)*64 + lq*8;
    short8 qf0 = *(const short8*)qp;
    short8 qf1 = *(const short8*)(qp + 32);
    f32x4 sacc[20];
    #pragma unroll
    for (int jt = 0; jt < 20; ++jt){
      const u16* kp = Ksrc + (size_t)(jt*16 + lm)*64 + lq*8;
      short8 kf0 = *(const short8*)kp;
      short8 kf1 = *(const short8*)(kp + 32);
      f32x4 a = zero4;
      a = __builtin_amdgcn_mfma_f32_16x16x32_bf16(qf0, kf0, a, 0, 0, 0);
      a = __builtin_amdgcn_mfma_f32_16x16x32_bf16(qf1, kf1, a, 0, 0, 0);
      sacc[jt] = a;
    }
    // full-row max BEFORE masking (reference semantics)
    float mx[4];
    #pragma unroll
    for (int r = 0; r < 4; ++r){
      float m = sacc[0][r];
      #pragma unroll
      for (int jt = 1; jt < 20; ++jt) m = fmaxf(m, sacc[jt][r]);
      mx[r] = m;
    }
    #pragma unroll
    for (int off = 1; off < 16; off <<= 1)
      #pragma unroll
      for (int r = 0; r < 4; ++r)
        mx[r] = fmaxf(mx[r], __shfl_xor(mx[r], off, 64));
    int gi[4];
    #pragma unroll
    for (int r = 0; r < 4; ++r) gi[r] = gls[qb + lq*4 + r];
    float sm[4] = {0.f, 0.f, 0.f, 0.f};
    #pragma unroll
    for (int jt = 0; jt < 20; ++jt){
      int j = jt*16 + lm;
      int gj = gls[j];
      #pragma unroll
      for (int r = 0; r < 4; ++r){
        float e = exp2f((sacc[jt][r] - mx[r]) * cexp);
        if ((gi[r] != 3) && (gj != 3) && (gi[r] != gj)) e = 0.f;  // ap==0 pairs
        sm[r] += e;
        Ps[(w*16 + lq*4 + r)*328 + j] = f2bf(e);
      }
    }
    #pragma unroll
    for (int off = 1; off < 16; off <<= 1)
      #pragma unroll
      for (int r = 0; r < 4; ++r)
        sm[r] += __shfl_xor(sm[r], off, 64);
    float inv[4];
    #pragma unroll
    for (int r = 0; r < 4; ++r) inv[r] = 1.0f / (sm[r] + 1e-6f);
    __syncthreads();   // drain Ps writes before A-layout reads
    // PV: out[16,64] = P[16,320] @ V[320,64]; V^T fragments from global
    f32x4 oacc[4];
    #pragma unroll
    for (int nt = 0; nt < 4; ++nt) oacc[nt] = zero4;
    #pragma unroll
    for (int ks = 0; ks < 10; ++ks){
      short8 pf = *(const short8*)&Ps[(w*16 + lm)*328 + ks*32 + lq*8];
      #pragma unroll
      for (int nt = 0; nt < 4; ++nt){
        short8 vf = *(const short8*)&Vsrc[(size_t)(nt*16 + lm)*320 + ks*32 + lq*8];
        oacc[nt] = __builtin_amdgcn_mfma_f32_16x16x32_bf16(pf, vf, oacc[nt], 0, 0, 0);
      }
    }
    #pragma unroll
    for (int nt = 0; nt < 4; ++nt){
      int d = nt*16 + lm;
      float vs = vsum[d];
      #pragma unroll
      for (int r = 0; r < 4; ++r){
        int row = qt*64 + w*16 + lq*4 + r;
        float v = (oacc[nt][r] + vs) * inv[r];
        aout[(size_t)(b*320 + row)*768 + h*64 + d] = f2bf(v);
      }
    }
    __syncthreads();   // Ps reuse next iteration
  }
}

// ---------- launch ----------
extern "C" void kernel_launch(void* const* d_in, const int* in_sizes, int n_in,
                              void* d_out, int out_size, void* d_ws, size_t ws_size,
                              hipStream_t stream)
{
  const float* x      = (const float*)d_in[0];
  const float* tmask  = (const float*)d_in[1];
  const float* qkv_w  = (const float*)d_in[2];
  const float* qkv_b  = (const float*)d_in[3];
  const float* proj_w = (const float*)d_in[4];
  const float* proj_b = (const float*)d_in[5];
  const float* dp1_w  = (const float*)d_in[6];
  const float* dp1_b  = (const float*)d_in[7];
  const float* dp2_w  = (const float*)d_in[8];
  const float* dp2_b  = (const float*)d_in[9];
  const float* dp3_w  = (const float*)d_in[10];
  const float* dp3_b  = (const float*)d_in[11];

  char* ws = (char*)d_ws;
  float* tgt    = (float*)(ws + 0);            // 32*768 f32        -> 98304
  float* tgtdp  = (float*)(ws + 98304);        // 32*384 f32        -> 147456
  float* h1     = (float*)(ws + 147456);       // 8192*384 f32      -> 12730368
  float* h2     = (float*)(ws + 12730368);     // 8192*192 f32      -> 19021824
  unsigned char* gid = (unsigned char*)(ws + 19021824);  // 10240   -> 19032064
  u16* xb     = (u16*)(ws + 19032064);         // 10240*768 bf16    -> 34760704
  u16* qkvwb  = (u16*)(ws + 34760704);         // 2304*768 bf16     -> 38299648
  u16* projwb = (u16*)(ws + 38299648);         // 768*768 bf16      -> 39479296
  u16* Qg     = (u16*)(ws + 39479296);         // [bh][320][64]     -> 55207936
  u16* Kg     = (u16*)(ws + 55207936);         //                   -> 70936576
  u16* Vg     = (u16*)(ws + 70936576);         // [bh][64][320]     -> 86665216
  u16* aout   = (u16*)(ws + 147456);           // bf16, overlaps dead h1/h2

  float* out = (float*)d_out;
  float* dec = out + 7864320;

  hipLaunchKernelGGL(k_cvt, dim3(7680), dim3(256), 0, stream, x, xb, 1966080);
  hipLaunchKernelGGL(k_cvt, dim3(1728), dim3(256), 0, stream, qkv_w, qkvwb, 442368);
  hipLaunchKernelGGL(k_cvt, dim3(576),  dim3(256), 0, stream, proj_w, projwb, 147456);
  hipLaunchKernelGGL(k_tgt,   dim3(32), dim3(256), 0, stream, x, tmask, tgt);
  hipLaunchKernelGGL(k_tgtdp, dim3(32), dim3(384), 0, stream, tgt, dp1_w, dp1_b, tgtdp);
  hipLaunchKernelGGL((k_sgemm<1,0>), dim3(128, 6), dim3(256), 0, stream,
                     x, 768, dp1_w, 1536, 768, (const float*)nullptr, tgtdp, h1, 384);
  hipLaunchKernelGGL((k_sgemm<0,1>), dim3(128, 3), dim3(256), 0, stream,
                     h1, 384, dp2_w, 384, 384, dp2_b, (const float*)nullptr, h2, 192);
  hipLaunchKernelGGL(k_decide, dim3(32), dim3(256), 0, stream, h2, dp3_w, dp3_b, dec, gid);
  hipLaunchKernelGGL((k_gemm<0>), dim3(80, 18), dim3(256), 0, stream,
                     xb, qkvwb, qkv_b, (float*)nullptr, Qg, Kg, Vg);
  hipLaunchKernelGGL(k_attn,  dim3(384), dim3(256), 0, stream, Qg, Kg, Vg, gid, aout);
  hipLaunchKernelGGL((k_gemm<1>), dim3(80, 6), dim3(256), 0, stream,
                     aout, projwb, proj_b, out, (u16*)nullptr, (u16*)nullptr, (u16*)nullptr);
}